// Round 21
// baseline (322.507 us; speedup 1.0000x reference)
//
#include <hip/hip_runtime.h>

// CrossAttention MI355X — round 21: r20 (270.4 µs) + T14 applied to the dwise
// residual loads in k_conv_all: xr_[8] (float4) issued at the END of phase A
// (hidden under MFMAs + barrier + stage_write), consumed in phase B. Same
// one-barrier liveness pattern as the proven sfa/sfb staging regs (no
// loop-carried state -> no r15-style spill). Everything else = r20.
//  k_conv_all      : q/k/v = in + dw3x3(pw @ in), h in 3-row LDS ring
//  k_gram          : G[b,h] = q @ k^T    (32x32x16 MFMA, 18 n-splits)
//  k_attn          : norms + softmax + M[b] = proj @ attn_blockdiag
//  k_gemm          : out = M[b] @ v      (f32 direct epilogue, 128 px/block)

#define B_  8
#define C_  96
#define W_  192
#define HW_ 36864
#define NB_ 32     // row-bands per image in k_conv (6 rows each)
#define NS_ 18     // k_gram n-splits (432 blocks -> single co-resident wave)

typedef __attribute__((ext_vector_type(8)))  short short8;
typedef __attribute__((ext_vector_type(4)))  float f32x4;
typedef __attribute__((ext_vector_type(16))) float f32x16;

__device__ __forceinline__ unsigned short f2b(float f){
  unsigned u = __float_as_uint(f);
  u += 0x7fffu + ((u >> 16) & 1u);
  return (unsigned short)(u >> 16);
}
__device__ __forceinline__ float blo(unsigned u){ return __uint_as_float(u << 16); }
__device__ __forceinline__ float bhi(unsigned u){ return __uint_as_float(u & 0xffff0000u); }

// Barrier waiting only on LDS ops (lgkmcnt), not global stores (vmcnt).
// All global->consumer deps here are same-thread register deps.
__device__ __forceinline__ void barrier_lds(){
  asm volatile("s_waitcnt lgkmcnt(0)\n\ts_barrier" ::: "memory");
}

// ---------------- k_conv_all: out = in + dw3x3(pw @ in), h in LDS ring -------
// grid (32 bands, 8 b, 3 conv), block 768 (12 waves), 153KB LDS (1 block/CU).
// GEMM: wave w = (mtg=w%6, ntg=w/6) -> 16 x 96 tile (18 MFMA, 3-reg afrag).
// Dwise: wave owns 8 channels, lanes 0..47 = 4-col groups.
// Per row r: phase A = issue stage-loads(r+1) + residual-loads(r-1) to regs,
// row-GEMM -> ring slot; phase B = stage-write(r+1) ∥ dwise(r-1).
__global__ __launch_bounds__(768, 1)
void k_conv_all(const float* __restrict__ x0, const float* __restrict__ x1,
                const float* __restrict__ x2,
                const float* __restrict__ pw0, const float* __restrict__ pw1,
                const float* __restrict__ pw2,
                const float* __restrict__ dw0, const float* __restrict__ dw1,
                const float* __restrict__ dw2,
                unsigned short* __restrict__ o0, unsigned short* __restrict__ o1,
                unsigned short* __restrict__ o2,
                float* __restrict__ n0, float* __restrict__ n1)
{
  __shared__ unsigned short xrow[192 * 104];      // 39,936 B  [pix][ch]
  __shared__ unsigned short hring[3][96 * 196];   // 112,896 B [slot][ch][1+col]

  const int t = threadIdx.x, lane = t & 63, wv = t >> 6;
  const int band = blockIdx.x, b = blockIdx.y, cid = blockIdx.z;
  const float* xsrc = (cid == 0) ? x0 : (cid == 1) ? x1 : x2;
  const float* pw   = (cid == 0) ? pw0 : (cid == 1) ? pw1 : pw2;
  const float* dwt  = (cid == 0) ? dw0 : (cid == 1) ? dw1 : dw2;
  unsigned short* outq = (cid == 0) ? o0 : (cid == 1) ? o1 : o2;
  float* nrm = (cid == 0) ? n0 : (cid == 1) ? n1 : nullptr;

  const int r0 = band * 6;
  const int l15 = lane & 15, l4 = lane >> 4;
  const int mtg = wv % 6, ntg = wv / 6;           // ntg 0..1
  const float* xb = xsrc + (size_t)b * C_ * HW_;

  // staging task decomposition: 2304 = 768 x 3 exactly
  int scp[3], spg[3];
  #pragma unroll
  for (int i = 0; i < 3; ++i){
    const int idx = i * 768 + t;
    scp[i] = idx / 48; spg[i] = idx - scp[i] * 48;
  }

  // pw A-frags in registers: single m-tile (16 rows) x 3 k-steps
  short8 afrag[3];
  #pragma unroll
  for (int ks = 0; ks < 3; ++ks){
    const int m = mtg * 16 + l15;
    const float* ap = pw + m * 96 + ks * 32 + l4 * 8;
    const float4 f0 = *(const float4*)ap;
    const float4 f1 = *(const float4*)(ap + 4);
    union { short8 v; unsigned short u[8]; } tmp;
    tmp.u[0]=f2b(f0.x); tmp.u[1]=f2b(f0.y); tmp.u[2]=f2b(f0.z); tmp.u[3]=f2b(f0.w);
    tmp.u[4]=f2b(f1.x); tmp.u[5]=f2b(f1.y); tmp.u[6]=f2b(f1.z); tmp.u[7]=f2b(f1.w);
    afrag[ks] = tmp.v;
  }

  // zero ring once (covers halo cols 0 and 193..195 permanently)
  {
    uint4* p = (uint4*)&hring[0][0];
    for (int i = t; i < 7056; i += 768) p[i] = make_uint4(0,0,0,0);
  }

  float ssq[8];
  #pragma unroll
  for (int i = 0; i < 8; ++i) ssq[i] = 0.f;

  auto stage_write = [&](const float4* fa, const float4* fb){
    #pragma unroll
    for (int i = 0; i < 3; ++i){
      const int pg = spg[i];
      const unsigned pk0 = (unsigned)f2b(fa[i].x) | ((unsigned)f2b(fb[i].x) << 16);
      const unsigned pk1 = (unsigned)f2b(fa[i].y) | ((unsigned)f2b(fb[i].y) << 16);
      const unsigned pk2 = (unsigned)f2b(fa[i].z) | ((unsigned)f2b(fb[i].z) << 16);
      const unsigned pk3 = (unsigned)f2b(fa[i].w) | ((unsigned)f2b(fb[i].w) << 16);
      const int s = (pg >> 1) & 3;                 // XOR-barrel bank spread
      const unsigned a0 = (s & 1) ? pk1 : pk0;
      const unsigned a1 = (s & 1) ? pk0 : pk1;
      const unsigned a2 = (s & 1) ? pk3 : pk2;
      const unsigned a3 = (s & 1) ? pk2 : pk3;
      const unsigned q0 = (s & 2) ? a2 : a0;
      const unsigned q1 = (s & 2) ? a3 : a1;
      const unsigned q2 = (s & 2) ? a0 : a2;
      const unsigned q3 = (s & 2) ? a1 : a3;
      unsigned short* basep = xrow + (4*pg) * 104 + 2*scp[i];
      *(unsigned*)(basep + ((0 ^ s) * 104)) = q0;
      *(unsigned*)(basep + ((1 ^ s) * 104)) = q1;
      *(unsigned*)(basep + ((2 ^ s) * 104)) = q2;
      *(unsigned*)(basep + ((3 ^ s) * 104)) = q3;
    }
  };
  auto stage_load = [&](int rs, float4* fa, float4* fb){
    #pragma unroll
    for (int i = 0; i < 3; ++i){
      const float* xp = xb + (size_t)(2*scp[i]) * HW_ + (size_t)rs * W_ + 4*spg[i];
      fa[i] = *(const float4*)xp;
      fb[i] = *(const float4*)(xp + HW_);
    }
  };

  // prologue: stage row r0-1 synchronously (if in image)
  if (r0 - 1 >= 0){
    float4 fa[3], fb[3];
    stage_load(r0 - 1, fa, fb);
    stage_write(fa, fb);
  }
  barrier_lds();

  #pragma unroll 1
  for (int r = r0 - 1; r <= r0 + 6; ++r){
    const int slot = (r + 3) % 3;
    const int rs = r + 1;
    const bool do_stage = (rs <= r0 + 6) && (rs < 192);
    const bool do_dw = (r - 1 >= r0) && (lane < 48);
    float4 sfa[3], sfb[3];
    if (do_stage) stage_load(rs, sfa, sfb);   // issue early; consumed in phase B

    // residual prefetch for dwise(r-1): issued in phase A, consumed in phase B
    float4 xr_[8];
    if (do_dw){
      const float* xrp = xb + (size_t)(r - 1) * W_ + 4*lane;
      #pragma unroll
      for (int cc = 0; cc < 8; ++cc)
        xr_[cc] = *(const float4*)(xrp + (size_t)(wv * 8 + cc) * HW_);
    }

    // ---- phase A: row GEMM h[96][192] = pw @ xrow  (or zero slot)
    if (r >= 0 && r < 192){
      f32x4 acc[6];
      #pragma unroll
      for (int nt = 0; nt < 6; ++nt){
        acc[nt][0]=0.f; acc[nt][1]=0.f; acc[nt][2]=0.f; acc[nt][3]=0.f;
      }
      #pragma unroll
      for (int ks = 0; ks < 3; ++ks){
        #pragma unroll
        for (int nt = 0; nt < 6; ++nt){
          const short8 bv = *(const short8*)(xrow + (ntg*96 + nt*16 + l15) * 104 + ks*32 + l4*8);
          acc[nt] = __builtin_amdgcn_mfma_f32_16x16x32_bf16(afrag[ks], bv, acc[nt], 0, 0, 0);
        }
      }
      unsigned short* hs = &hring[slot][0];
      #pragma unroll
      for (int nt = 0; nt < 6; ++nt)
        #pragma unroll
        for (int reg = 0; reg < 4; ++reg){
          const int m = mtg*16 + l4*4 + reg;            // out-ch
          const int n = ntg*96 + nt*16 + l15;           // pix col
          hs[m * 196 + 1 + n] = f2b(acc[nt][reg]);
        }
    } else {
      uint4* p = (uint4*)&hring[slot][0];
      for (int i = t; i < 2352; i += 768) p[i] = make_uint4(0,0,0,0);
    }
    barrier_lds();   // ring row r ready; xrow free

    // ---- phase B: stage-write(r+1) ∥ dwise(r-1)
    if (do_stage) stage_write(sfa, sfb);
    if (r - 1 >= r0){
      const int rr = r - 1;
      const unsigned short* h0 = &hring[(rr + 2) % 3][0];   // row rr-1
      const unsigned short* h1 = &hring[(rr + 3) % 3][0];   // row rr
      const unsigned short* h2 = &hring[(rr + 4) % 3][0];   // row rr+1
      if (lane < 48){
        const int g = lane;
        #pragma unroll
        for (int cc = 0; cc < 8; ++cc){
          const int chs = __builtin_amdgcn_readfirstlane(wv * 8 + cc);
          float wgt[9];
          #pragma unroll
          for (int i = 0; i < 9; ++i) wgt[i] = dwt[chs * 9 + i];   // s_load
          const int rb = chs * 196 + 4 * g;
          float hv[3][6];
          {
            const unsigned short* hp[3] = {h0 + rb, h1 + rb, h2 + rb};
            #pragma unroll
            for (int d = 0; d < 3; ++d){
              const uint2 ua = *(const uint2*)(hp[d]);           // imgcols 4g-1..4g+2
              const unsigned ub = *(const unsigned*)(hp[d] + 4); // imgcols 4g+3,4g+4
              hv[d][0]=blo(ua.x); hv[d][1]=bhi(ua.x); hv[d][2]=blo(ua.y);
              hv[d][3]=bhi(ua.y); hv[d][4]=blo(ub);   hv[d][5]=bhi(ub);
            }
          }
          float o[4] = {xr_[cc].x, xr_[cc].y, xr_[cc].z, xr_[cc].w};
          #pragma unroll
          for (int j = 0; j < 4; ++j){
            float s = o[j];
            #pragma unroll
            for (int d = 0; d < 3; ++d){
              s = fmaf(wgt[d*3+0], hv[d][j],   s);
              s = fmaf(wgt[d*3+1], hv[d][j+1], s);
              s = fmaf(wgt[d*3+2], hv[d][j+2], s);
            }
            o[j] = s;
            ssq[cc] = fmaf(s, s, ssq[cc]);
          }
          const size_t cb = (size_t)(b * C_ + chs) * HW_ + (size_t)rr * W_ + 4*g;
          const unsigned p0 = (unsigned)f2b(o[0]) | ((unsigned)f2b(o[1]) << 16);
          const unsigned p1 = (unsigned)f2b(o[2]) | ((unsigned)f2b(o[3]) << 16);
          *(uint2*)(outq + cb) = make_uint2(p0, p1);
        }
      }
    }
    barrier_lds();   // xrow(r+1) ready; ring slot (r+1)%3 free for overwrite
  }

  if (nrm){
    #pragma unroll
    for (int cc = 0; cc < 8; ++cc){
      float s = ssq[cc];                     // lanes 48..63 contribute 0
      #pragma unroll
      for (int off = 32; off; off >>= 1) s += __shfl_xor(s, off);
      if (lane == 0)
        nrm[((size_t)b * NB_ + band) * C_ + wv * 8 + cc] = s;
    }
  }
}

// ---------------- k_gemm: out[96][36864] = M(96x96,per-b) @ v ----------------
// grid (288, 8), block 256 (4 waves), 3 blocks/CU (46.6KB LDS): 2304 blocks =
// exactly 3.0 co-resident waves. Wave w owns pixels [w*32, w*32+32).
__global__ __launch_bounds__(256, 3)
void k_gemm(const unsigned short* __restrict__ Bsrc, const float* __restrict__ Asrc,
            float* __restrict__ Dst)
{
  __shared__ unsigned short xT[128 * 104];   // 26,624 B  [pix][ch]
  __shared__ unsigned short aw[96 * 104];    // 19,968 B  [m][k]
  const int t = threadIdx.x;
  const int b = blockIdx.y;
  const int p0 = blockIdx.x * 128;
  const int lane = t & 63, w = t >> 6;
  const int l15 = lane & 15, l4 = lane >> 4;

  const float* Ab = Asrc + b * C_ * C_;
  #pragma unroll
  for (int j = 0; j < 18; ++j){
    const int pi = j * 256 + t;
    const int row = pi / 48, c2 = (pi - row * 48) * 2;
    const float a0 = Ab[row * 96 + c2], a1 = Ab[row * 96 + c2 + 1];
    *(unsigned*)(aw + row * 104 + c2) = (unsigned)f2b(a0) | ((unsigned)f2b(a1) << 16);
  }
  // stage v tile transposed: 1536 tasks = 48 ch-pairs x 32 pixel-quads
  #pragma unroll 1
  for (int i = 0; i < 6; ++i){
    const int idx = i * 256 + t;
    const int cp = idx >> 5, pg = idx & 31;
    const unsigned short* vp = Bsrc + (size_t)b * C_ * HW_ + (size_t)(2*cp) * HW_ + p0 + 4*pg;
    const uint2 ua = *(const uint2*)vp;          // 4 px of ch 2cp
    const uint2 ub = *(const uint2*)(vp + HW_);  // 4 px of ch 2cp+1
    const unsigned pk0 = (ua.x & 0xffffu) | (ub.x << 16);
    const unsigned pk1 = (ua.x >> 16)     | (ub.x & 0xffff0000u);
    const unsigned pk2 = (ua.y & 0xffffu) | (ub.y << 16);
    const unsigned pk3 = (ua.y >> 16)     | (ub.y & 0xffff0000u);
    const int s = (pg >> 1) & 3;
    const unsigned a0 = (s & 1) ? pk1 : pk0;
    const unsigned a1 = (s & 1) ? pk0 : pk1;
    const unsigned a2 = (s & 1) ? pk3 : pk2;
    const unsigned a3 = (s & 1) ? pk2 : pk3;
    const unsigned q0 = (s & 2) ? a2 : a0;
    const unsigned q1 = (s & 2) ? a3 : a1;
    const unsigned q2 = (s & 2) ? a0 : a2;
    const unsigned q3 = (s & 2) ? a1 : a3;
    unsigned short* basep = xT + (4*pg) * 104 + 2*cp;
    *(unsigned*)(basep + ((0 ^ s) * 104)) = q0;
    *(unsigned*)(basep + ((1 ^ s) * 104)) = q1;
    *(unsigned*)(basep + ((2 ^ s) * 104)) = q2;
    *(unsigned*)(basep + ((3 ^ s) * 104)) = q3;
  }
  __syncthreads();

  f32x4 acc[6][2];
  #pragma unroll
  for (int i = 0; i < 6; ++i)
    #pragma unroll
    for (int j = 0; j < 2; ++j){ acc[i][j][0]=0.f; acc[i][j][1]=0.f; acc[i][j][2]=0.f; acc[i][j][3]=0.f; }

  #pragma unroll
  for (int ks = 0; ks < 3; ++ks){
    short8 a[6];
    #pragma unroll
    for (int mt = 0; mt < 6; ++mt)
      a[mt] = *(const short8*)(aw + (mt * 16 + l15) * 104 + ks * 32 + l4 * 8);
    #pragma unroll
    for (int nt = 0; nt < 2; ++nt){
      const short8 bv = *(const short8*)(xT + (w * 32 + nt * 16 + l15) * 104 + ks * 32 + l4 * 8);
      #pragma unroll
      for (int mt = 0; mt < 6; ++mt)
        acc[mt][nt] = __builtin_amdgcn_mfma_f32_16x16x32_bf16(a[mt], bv, acc[mt][nt], 0, 0, 0);
    }
  }

  float* D = Dst + (size_t)b * C_ * HW_ + p0;
  #pragma unroll
  for (int mt = 0; mt < 6; ++mt)
    #pragma unroll
    for (int nt = 0; nt < 2; ++nt)
      #pragma unroll
      for (int r = 0; r < 4; ++r)
        D[(size_t)(mt * 16 + l4 * 4 + r) * HW_ + w * 32 + nt * 16 + l15] = acc[mt][nt][r];
}

// ---------------- k_gram: G[b,h] = q_bh @ k_bh^T ----------------
// grid (18 ns, 24 bh), block 256 (4 waves): 432 blocks <= 512 co-resident
// slots -> no straggler wave. Per block: 2048-px chunk, 4 rounds of 512-px
// panels [32ch][520px] (straight-copy staging).
__global__ __launch_bounds__(256, 2)
void k_gram(const unsigned short* __restrict__ qb, const unsigned short* __restrict__ kb,
            float* __restrict__ Gp)
{
  __shared__ unsigned short pan[2][32 * 520];   // 66,560 B
  const int t = threadIdx.x, lane = t & 63, w = t >> 6;
  const int ns = blockIdx.x, bh = blockIdx.y;
  const int b = bh / 3, h = bh - b * 3;
  const size_t base = ((size_t)b * C_ + h * 32) * HW_ + ns * 2048;
  const int l31 = lane & 31, l5 = lane >> 5;

  f32x16 acc;
  #pragma unroll
  for (int r = 0; r < 16; ++r) acc[r] = 0.f;

  #pragma unroll 1
  for (int rd = 0; rd < 4; ++rd){
    __syncthreads();
    #pragma unroll 8
    for (int j = 0; j < 64; ++j){
      const int idx = j * 256 + t;
      const int op = idx >> 13;
      const int rem = idx & 8191;
      const int ch = rem >> 8, dcol = rem & 255;
      const unsigned* src = (const unsigned*)((op ? kb : qb) + base + (size_t)ch * HW_ + rd * 512) + dcol;
      *(unsigned*)(&pan[op][ch * 520 + dcol * 2]) = *src;
    }
    __syncthreads();
    #pragma unroll
    for (int j8 = 0; j8 < 8; ++j8){
      const int s = j8 * 4 + w;
      const short8 av = *(const short8*)(&pan[0][l31 * 520 + s * 16 + l5 * 8]);
      const short8 bv = *(const short8*)(&pan[1][l31 * 520 + s * 16 + l5 * 8]);
      acc = __builtin_amdgcn_mfma_f32_32x32x16_bf16(av, bv, acc, 0, 0, 0);
    }
  }
  __syncthreads();
  float* red = (float*)pan;
  #pragma unroll
  for (int r = 0; r < 16; ++r) red[w * 1024 + r * 64 + lane] = acc[r];
  __syncthreads();
  #pragma unroll
  for (int q = 0; q < 4; ++q){
    const int fi = q * 256 + t;
    const float v = red[fi] + red[1024 + fi] + red[2048 + fi] + red[3072 + fi];
    const int rr = fi >> 6, ll = fi & 63;
    const int c = (rr & 3) + 8 * (rr >> 2) + 4 * (ll >> 5);   // m101 C-layout
    const int d = ll & 31;
    Gp[(((size_t)ns * 24 + bh) * 32 + c) * 32 + d] = v;
  }
}

// ---------------- k_attn: norms + softmax + M = proj @ attn_bd ----------------
__global__ __launch_bounds__(256)
void k_attn(const float* __restrict__ Gp, const float* __restrict__ qqp,
            const float* __restrict__ kkp, const float* __restrict__ temp,
            const float* __restrict__ proj, float* __restrict__ M)
{
  const int b = blockIdx.x, t = threadIdx.x;
  __shared__ float at[3][32][32];
  __shared__ float ninv[2][C_];
  if (t < 2 * C_){
    const int kind = t / C_, r = t - kind * C_;
    const float* P = kind ? kkp : qqp;
    float s = 0.f;
    #pragma unroll
    for (int ns = 0; ns < NB_; ++ns) s += P[((size_t)b * NB_ + ns) * C_ + r];
    ninv[kind][r] = 1.f / fmaxf(sqrtf(s), 1e-12f);
  }
  __syncthreads();
  for (int idx = t; idx < 3 * 1024; idx += 256){
    const int h = idx >> 10, rem = idx & 1023, cc = rem >> 5, dd = rem & 31;
    float g = 0.f;
    #pragma unroll
    for (int ns = 0; ns < NS_; ++ns)
      g += Gp[(((size_t)ns * 24 + b * 3 + h) * 32 + cc) * 32 + dd];
    at[h][cc][dd] = g * ninv[0][h * 32 + cc] * ninv[1][h * 32 + dd] * temp[h];
  }
  __syncthreads();
  if (t < C_){
    const int h = t >> 5, cc = t & 31;
    float m = -1e30f;
    for (int dd = 0; dd < 32; ++dd) m = fmaxf(m, at[h][cc][dd]);
    float s = 0.f;
    for (int dd = 0; dd < 32; ++dd){ const float e = expf(at[h][cc][dd] - m); at[h][cc][dd] = e; s += e; }
    const float inv = 1.f / s;
    for (int dd = 0; dd < 32; ++dd) at[h][cc][dd] *= inv;
  }
  __syncthreads();
  for (int idx = t; idx < C_ * C_; idx += 256){
    const int o = idx / 96, hd = idx - o * 96, h = hd >> 5, dd = hd & 31;
    float m = 0.f;
    #pragma unroll
    for (int cc = 0; cc < 32; ++cc)
      m = fmaf(proj[o * 96 + h * 32 + cc], at[h][cc][dd], m);
    M[(size_t)b * 9216 + idx] = m;
  }
}

extern "C" void kernel_launch(void* const* d_in, const int* in_sizes, int n_in,
                              void* d_out, int out_size, void* d_ws, size_t ws_size,
                              hipStream_t stream)
{
  const float* x     = (const float*)d_in[0];
  const float* y     = (const float*)d_in[1];
  const float* z     = (const float*)d_in[2];
  const float* temp  = (const float*)d_in[3];
  const float* q_pwc = (const float*)d_in[4];
  const float* q_dwc = (const float*)d_in[5];
  const float* k_pwc = (const float*)d_in[6];
  const float* k_dwc = (const float*)d_in[7];
  const float* v_pwc = (const float*)d_in[8];
  const float* v_dwc = (const float*)d_in[9];
  const float* proj  = (const float*)d_in[10];

  // workspace layout
  char* ws = (char*)d_ws;
  unsigned short* qb = (unsigned short*)(ws + 56623104);
  unsigned short* kb = (unsigned short*)(ws + 113246208);
  unsigned short* vb = (unsigned short*)(ws + 169869312);      // end 226,492,416
  float* qqp = (float*)(ws + 226492416);                       // 98,304
  float* kkp = (float*)(ws + 226590720);                       // 98,304
  float* Gp  = (float*)(ws + 4194304);                         // 1,769,472 (free region)
  float* M   = (float*)(ws + 8388608);                         // 294,912 (free region)
  float* out = (float*)d_out;

  k_conv_all<<<dim3(NB_, B_, 3), 768, 0, stream>>>(
      x, y, z, q_pwc, k_pwc, v_pwc, q_dwc, k_dwc, v_dwc, qb, kb, vb, qqp, kkp);
  k_gram<<<dim3(NS_, 24), 256, 0, stream>>>(qb, kb, Gp);
  k_attn<<<B_, 256, 0, stream>>>(Gp, qqp, kkp, temp, proj, M);
  k_gemm<<<dim3(HW_ / 128, B_), 256, 0, stream>>>(vb, M, out);
}

// Round 22
// 271.063 us; speedup vs baseline: 1.1898x; 1.1898x over previous
//
#include <hip/hip_runtime.h>

// CrossAttention MI355X — round 22: byte-exact revert to round 20 (270.4 µs,
// session best). r21's residual-prefetch (T14 on xr_) spilled across the
// barrier (WRITE 212MB vs 168MB, FETCH +60MB, VGPR pinned at 84) — fifth
// confirmation that extending reg-state across barrier_lds beyond the r13
// baseline triggers allocator spills at this LDS footprint. Final state:
//  k_conv_all      : q/k/v = in + dw3x3(pw @ in), h in 3-row LDS ring
//  k_gram          : G[b,h] = q @ k^T    (32x32x16 MFMA, 18 n-splits)
//  k_attn          : norms + softmax + M[b] = proj @ attn_blockdiag
//  k_gemm          : out = M[b] @ v      (f32 direct epilogue, 128 px/block)

#define B_  8
#define C_  96
#define W_  192
#define HW_ 36864
#define NB_ 32     // row-bands per image in k_conv (6 rows each)
#define NS_ 18     // k_gram n-splits (432 blocks -> single co-resident wave)

typedef __attribute__((ext_vector_type(8)))  short short8;
typedef __attribute__((ext_vector_type(4)))  float f32x4;
typedef __attribute__((ext_vector_type(16))) float f32x16;

__device__ __forceinline__ unsigned short f2b(float f){
  unsigned u = __float_as_uint(f);
  u += 0x7fffu + ((u >> 16) & 1u);
  return (unsigned short)(u >> 16);
}
__device__ __forceinline__ float blo(unsigned u){ return __uint_as_float(u << 16); }
__device__ __forceinline__ float bhi(unsigned u){ return __uint_as_float(u & 0xffff0000u); }

// Barrier waiting only on LDS ops (lgkmcnt), not global stores (vmcnt).
// All global->consumer deps here are same-thread register deps.
__device__ __forceinline__ void barrier_lds(){
  asm volatile("s_waitcnt lgkmcnt(0)\n\ts_barrier" ::: "memory");
}

// ---------------- k_conv_all: out = in + dw3x3(pw @ in), h in LDS ring -------
// grid (32 bands, 8 b, 3 conv), block 768 (12 waves), 153KB LDS (1 block/CU).
// GEMM: wave w = (mtg=w%6, ntg=w/6) -> 16 x 96 tile (18 MFMA, 3-reg afrag).
// Dwise: wave owns 8 channels, lanes 0..47 = 4-col groups.
// Per row r: phase A = issue stage-loads(r+1) to regs, row-GEMM -> ring slot;
// phase B = reg->LDS stage-write(r+1) ∥ dwise(r-1).
__global__ __launch_bounds__(768, 1)
void k_conv_all(const float* __restrict__ x0, const float* __restrict__ x1,
                const float* __restrict__ x2,
                const float* __restrict__ pw0, const float* __restrict__ pw1,
                const float* __restrict__ pw2,
                const float* __restrict__ dw0, const float* __restrict__ dw1,
                const float* __restrict__ dw2,
                unsigned short* __restrict__ o0, unsigned short* __restrict__ o1,
                unsigned short* __restrict__ o2,
                float* __restrict__ n0, float* __restrict__ n1)
{
  __shared__ unsigned short xrow[192 * 104];      // 39,936 B  [pix][ch]
  __shared__ unsigned short hring[3][96 * 196];   // 112,896 B [slot][ch][1+col]

  const int t = threadIdx.x, lane = t & 63, wv = t >> 6;
  const int band = blockIdx.x, b = blockIdx.y, cid = blockIdx.z;
  const float* xsrc = (cid == 0) ? x0 : (cid == 1) ? x1 : x2;
  const float* pw   = (cid == 0) ? pw0 : (cid == 1) ? pw1 : pw2;
  const float* dwt  = (cid == 0) ? dw0 : (cid == 1) ? dw1 : dw2;
  unsigned short* outq = (cid == 0) ? o0 : (cid == 1) ? o1 : o2;
  float* nrm = (cid == 0) ? n0 : (cid == 1) ? n1 : nullptr;

  const int r0 = band * 6;
  const int l15 = lane & 15, l4 = lane >> 4;
  const int mtg = wv % 6, ntg = wv / 6;           // ntg 0..1
  const float* xb = xsrc + (size_t)b * C_ * HW_;

  // staging task decomposition: 2304 = 768 x 3 exactly
  int scp[3], spg[3];
  #pragma unroll
  for (int i = 0; i < 3; ++i){
    const int idx = i * 768 + t;
    scp[i] = idx / 48; spg[i] = idx - scp[i] * 48;
  }

  // pw A-frags in registers: single m-tile (16 rows) x 3 k-steps
  short8 afrag[3];
  #pragma unroll
  for (int ks = 0; ks < 3; ++ks){
    const int m = mtg * 16 + l15;
    const float* ap = pw + m * 96 + ks * 32 + l4 * 8;
    const float4 f0 = *(const float4*)ap;
    const float4 f1 = *(const float4*)(ap + 4);
    union { short8 v; unsigned short u[8]; } tmp;
    tmp.u[0]=f2b(f0.x); tmp.u[1]=f2b(f0.y); tmp.u[2]=f2b(f0.z); tmp.u[3]=f2b(f0.w);
    tmp.u[4]=f2b(f1.x); tmp.u[5]=f2b(f1.y); tmp.u[6]=f2b(f1.z); tmp.u[7]=f2b(f1.w);
    afrag[ks] = tmp.v;
  }

  // zero ring once (covers halo cols 0 and 193..195 permanently)
  {
    uint4* p = (uint4*)&hring[0][0];
    for (int i = t; i < 7056; i += 768) p[i] = make_uint4(0,0,0,0);
  }

  float ssq[8];
  #pragma unroll
  for (int i = 0; i < 8; ++i) ssq[i] = 0.f;

  auto stage_write = [&](const float4* fa, const float4* fb){
    #pragma unroll
    for (int i = 0; i < 3; ++i){
      const int pg = spg[i];
      const unsigned pk0 = (unsigned)f2b(fa[i].x) | ((unsigned)f2b(fb[i].x) << 16);
      const unsigned pk1 = (unsigned)f2b(fa[i].y) | ((unsigned)f2b(fb[i].y) << 16);
      const unsigned pk2 = (unsigned)f2b(fa[i].z) | ((unsigned)f2b(fb[i].z) << 16);
      const unsigned pk3 = (unsigned)f2b(fa[i].w) | ((unsigned)f2b(fb[i].w) << 16);
      const int s = (pg >> 1) & 3;                 // XOR-barrel bank spread
      const unsigned a0 = (s & 1) ? pk1 : pk0;
      const unsigned a1 = (s & 1) ? pk0 : pk1;
      const unsigned a2 = (s & 1) ? pk3 : pk2;
      const unsigned a3 = (s & 1) ? pk2 : pk3;
      const unsigned q0 = (s & 2) ? a2 : a0;
      const unsigned q1 = (s & 2) ? a3 : a1;
      const unsigned q2 = (s & 2) ? a0 : a2;
      const unsigned q3 = (s & 2) ? a1 : a3;
      unsigned short* basep = xrow + (4*pg) * 104 + 2*scp[i];
      *(unsigned*)(basep + ((0 ^ s) * 104)) = q0;
      *(unsigned*)(basep + ((1 ^ s) * 104)) = q1;
      *(unsigned*)(basep + ((2 ^ s) * 104)) = q2;
      *(unsigned*)(basep + ((3 ^ s) * 104)) = q3;
    }
  };
  auto stage_load = [&](int rs, float4* fa, float4* fb){
    #pragma unroll
    for (int i = 0; i < 3; ++i){
      const float* xp = xb + (size_t)(2*scp[i]) * HW_ + (size_t)rs * W_ + 4*spg[i];
      fa[i] = *(const float4*)xp;
      fb[i] = *(const float4*)(xp + HW_);
    }
  };

  // prologue: stage row r0-1 synchronously (if in image)
  if (r0 - 1 >= 0){
    float4 fa[3], fb[3];
    stage_load(r0 - 1, fa, fb);
    stage_write(fa, fb);
  }
  barrier_lds();

  #pragma unroll 1
  for (int r = r0 - 1; r <= r0 + 6; ++r){
    const int slot = (r + 3) % 3;
    const int rs = r + 1;
    const bool do_stage = (rs <= r0 + 6) && (rs < 192);
    float4 sfa[3], sfb[3];
    if (do_stage) stage_load(rs, sfa, sfb);   // issue early; consumed in phase B

    // ---- phase A: row GEMM h[96][192] = pw @ xrow  (or zero slot)
    if (r >= 0 && r < 192){
      f32x4 acc[6];
      #pragma unroll
      for (int nt = 0; nt < 6; ++nt){
        acc[nt][0]=0.f; acc[nt][1]=0.f; acc[nt][2]=0.f; acc[nt][3]=0.f;
      }
      #pragma unroll
      for (int ks = 0; ks < 3; ++ks){
        #pragma unroll
        for (int nt = 0; nt < 6; ++nt){
          const short8 bv = *(const short8*)(xrow + (ntg*96 + nt*16 + l15) * 104 + ks*32 + l4*8);
          acc[nt] = __builtin_amdgcn_mfma_f32_16x16x32_bf16(afrag[ks], bv, acc[nt], 0, 0, 0);
        }
      }
      unsigned short* hs = &hring[slot][0];
      #pragma unroll
      for (int nt = 0; nt < 6; ++nt)
        #pragma unroll
        for (int reg = 0; reg < 4; ++reg){
          const int m = mtg*16 + l4*4 + reg;            // out-ch
          const int n = ntg*96 + nt*16 + l15;           // pix col
          hs[m * 196 + 1 + n] = f2b(acc[nt][reg]);
        }
    } else {
      uint4* p = (uint4*)&hring[slot][0];
      for (int i = t; i < 2352; i += 768) p[i] = make_uint4(0,0,0,0);
    }
    barrier_lds();   // ring row r ready; xrow free

    // ---- phase B: stage-write(r+1) ∥ dwise(r-1)
    if (do_stage) stage_write(sfa, sfb);
    if (r - 1 >= r0){
      const int rr = r - 1;
      const unsigned short* h0 = &hring[(rr + 2) % 3][0];   // row rr-1
      const unsigned short* h1 = &hring[(rr + 3) % 3][0];   // row rr
      const unsigned short* h2 = &hring[(rr + 4) % 3][0];   // row rr+1
      if (lane < 48){
        const int g = lane;
        float4 xr_[8];                       // hoisted residual prefetch
        const float* xrp = xb + (size_t)rr * W_ + 4*g;
        #pragma unroll
        for (int cc = 0; cc < 8; ++cc)
          xr_[cc] = *(const float4*)(xrp + (size_t)(wv * 8 + cc) * HW_);
        #pragma unroll
        for (int cc = 0; cc < 8; ++cc){
          const int chs = __builtin_amdgcn_readfirstlane(wv * 8 + cc);
          float wgt[9];
          #pragma unroll
          for (int i = 0; i < 9; ++i) wgt[i] = dwt[chs * 9 + i];   // s_load
          const int rb = chs * 196 + 4 * g;
          float hv[3][6];
          {
            const unsigned short* hp[3] = {h0 + rb, h1 + rb, h2 + rb};
            #pragma unroll
            for (int d = 0; d < 3; ++d){
              const uint2 ua = *(const uint2*)(hp[d]);           // imgcols 4g-1..4g+2
              const unsigned ub = *(const unsigned*)(hp[d] + 4); // imgcols 4g+3,4g+4
              hv[d][0]=blo(ua.x); hv[d][1]=bhi(ua.x); hv[d][2]=blo(ua.y);
              hv[d][3]=bhi(ua.y); hv[d][4]=blo(ub);   hv[d][5]=bhi(ub);
            }
          }
          float o[4] = {xr_[cc].x, xr_[cc].y, xr_[cc].z, xr_[cc].w};
          #pragma unroll
          for (int j = 0; j < 4; ++j){
            float s = o[j];
            #pragma unroll
            for (int d = 0; d < 3; ++d){
              s = fmaf(wgt[d*3+0], hv[d][j],   s);
              s = fmaf(wgt[d*3+1], hv[d][j+1], s);
              s = fmaf(wgt[d*3+2], hv[d][j+2], s);
            }
            o[j] = s;
            ssq[cc] = fmaf(s, s, ssq[cc]);
          }
          const size_t cb = (size_t)(b * C_ + chs) * HW_ + (size_t)rr * W_ + 4*g;
          const unsigned p0 = (unsigned)f2b(o[0]) | ((unsigned)f2b(o[1]) << 16);
          const unsigned p1 = (unsigned)f2b(o[2]) | ((unsigned)f2b(o[3]) << 16);
          *(uint2*)(outq + cb) = make_uint2(p0, p1);
        }
      }
    }
    barrier_lds();   // xrow(r+1) ready; ring slot (r+1)%3 free for overwrite
  }

  if (nrm){
    #pragma unroll
    for (int cc = 0; cc < 8; ++cc){
      float s = ssq[cc];                     // lanes 48..63 contribute 0
      #pragma unroll
      for (int off = 32; off; off >>= 1) s += __shfl_xor(s, off);
      if (lane == 0)
        nrm[((size_t)b * NB_ + band) * C_ + wv * 8 + cc] = s;
    }
  }
}

// ---------------- k_gemm: out[96][36864] = M(96x96,per-b) @ v ----------------
// grid (288, 8), block 256 (4 waves), 3 blocks/CU (46.6KB LDS): 2304 blocks =
// exactly 3.0 co-resident waves. Wave w owns pixels [w*32, w*32+32).
// v staged transposed [pix][104ch] via uint2 loads + pair-pack + XOR-barrel.
__global__ __launch_bounds__(256, 3)
void k_gemm(const unsigned short* __restrict__ Bsrc, const float* __restrict__ Asrc,
            float* __restrict__ Dst)
{
  __shared__ unsigned short xT[128 * 104];   // 26,624 B  [pix][ch]
  __shared__ unsigned short aw[96 * 104];    // 19,968 B  [m][k]
  const int t = threadIdx.x;
  const int b = blockIdx.y;
  const int p0 = blockIdx.x * 128;
  const int lane = t & 63, w = t >> 6;
  const int l15 = lane & 15, l4 = lane >> 4;

  const float* Ab = Asrc + b * C_ * C_;
  #pragma unroll
  for (int j = 0; j < 18; ++j){
    const int pi = j * 256 + t;
    const int row = pi / 48, c2 = (pi - row * 48) * 2;
    const float a0 = Ab[row * 96 + c2], a1 = Ab[row * 96 + c2 + 1];
    *(unsigned*)(aw + row * 104 + c2) = (unsigned)f2b(a0) | ((unsigned)f2b(a1) << 16);
  }
  // stage v tile transposed: 1536 tasks = 48 ch-pairs x 32 pixel-quads
  #pragma unroll 1
  for (int i = 0; i < 6; ++i){
    const int idx = i * 256 + t;
    const int cp = idx >> 5, pg = idx & 31;
    const unsigned short* vp = Bsrc + (size_t)b * C_ * HW_ + (size_t)(2*cp) * HW_ + p0 + 4*pg;
    const uint2 ua = *(const uint2*)vp;          // 4 px of ch 2cp
    const uint2 ub = *(const uint2*)(vp + HW_);  // 4 px of ch 2cp+1
    const unsigned pk0 = (ua.x & 0xffffu) | (ub.x << 16);
    const unsigned pk1 = (ua.x >> 16)     | (ub.x & 0xffff0000u);
    const unsigned pk2 = (ua.y & 0xffffu) | (ub.y << 16);
    const unsigned pk3 = (ua.y >> 16)     | (ub.y & 0xffff0000u);
    const int s = (pg >> 1) & 3;
    const unsigned a0 = (s & 1) ? pk1 : pk0;
    const unsigned a1 = (s & 1) ? pk0 : pk1;
    const unsigned a2 = (s & 1) ? pk3 : pk2;
    const unsigned a3 = (s & 1) ? pk2 : pk3;
    const unsigned q0 = (s & 2) ? a2 : a0;
    const unsigned q1 = (s & 2) ? a3 : a1;
    const unsigned q2 = (s & 2) ? a0 : a2;
    const unsigned q3 = (s & 2) ? a1 : a3;
    unsigned short* basep = xT + (4*pg) * 104 + 2*cp;
    *(unsigned*)(basep + ((0 ^ s) * 104)) = q0;
    *(unsigned*)(basep + ((1 ^ s) * 104)) = q1;
    *(unsigned*)(basep + ((2 ^ s) * 104)) = q2;
    *(unsigned*)(basep + ((3 ^ s) * 104)) = q3;
  }
  __syncthreads();

  f32x4 acc[6][2];
  #pragma unroll
  for (int i = 0; i < 6; ++i)
    #pragma unroll
    for (int j = 0; j < 2; ++j){ acc[i][j][0]=0.f; acc[i][j][1]=0.f; acc[i][j][2]=0.f; acc[i][j][3]=0.f; }

  #pragma unroll
  for (int ks = 0; ks < 3; ++ks){
    short8 a[6];
    #pragma unroll
    for (int mt = 0; mt < 6; ++mt)
      a[mt] = *(const short8*)(aw + (mt * 16 + l15) * 104 + ks * 32 + l4 * 8);
    #pragma unroll
    for (int nt = 0; nt < 2; ++nt){
      const short8 bv = *(const short8*)(xT + (w * 32 + nt * 16 + l15) * 104 + ks * 32 + l4 * 8);
      #pragma unroll
      for (int mt = 0; mt < 6; ++mt)
        acc[mt][nt] = __builtin_amdgcn_mfma_f32_16x16x32_bf16(a[mt], bv, acc[mt][nt], 0, 0, 0);
    }
  }

  float* D = Dst + (size_t)b * C_ * HW_ + p0;
  #pragma unroll
  for (int mt = 0; mt < 6; ++mt)
    #pragma unroll
    for (int nt = 0; nt < 2; ++nt)
      #pragma unroll
      for (int r = 0; r < 4; ++r)
        D[(size_t)(mt * 16 + l4 * 4 + r) * HW_ + w * 32 + nt * 16 + l15] = acc[mt][nt][r];
}

// ---------------- k_gram: G[b,h] = q_bh @ k_bh^T ----------------
// grid (18 ns, 24 bh), block 256 (4 waves): 432 blocks <= 512 co-resident
// slots -> no straggler wave. Per block: 2048-px chunk, 4 rounds of 512-px
// panels [32ch][520px] (straight-copy staging).
__global__ __launch_bounds__(256, 2)
void k_gram(const unsigned short* __restrict__ qb, const unsigned short* __restrict__ kb,
            float* __restrict__ Gp)
{
  __shared__ unsigned short pan[2][32 * 520];   // 66,560 B
  const int t = threadIdx.x, lane = t & 63, w = t >> 6;
  const int ns = blockIdx.x, bh = blockIdx.y;
  const int b = bh / 3, h = bh - b * 3;
  const size_t base = ((size_t)b * C_ + h * 32) * HW_ + ns * 2048;
  const int l31 = lane & 31, l5 = lane >> 5;

  f32x16 acc;
  #pragma unroll
  for (int r = 0; r < 16; ++r) acc[r] = 0.f;

  #pragma unroll 1
  for (int rd = 0; rd < 4; ++rd){
    __syncthreads();
    #pragma unroll 8
    for (int j = 0; j < 64; ++j){
      const int idx = j * 256 + t;
      const int op = idx >> 13;
      const int rem = idx & 8191;
      const int ch = rem >> 8, dcol = rem & 255;
      const unsigned* src = (const unsigned*)((op ? kb : qb) + base + (size_t)ch * HW_ + rd * 512) + dcol;
      *(unsigned*)(&pan[op][ch * 520 + dcol * 2]) = *src;
    }
    __syncthreads();
    #pragma unroll
    for (int j8 = 0; j8 < 8; ++j8){
      const int s = j8 * 4 + w;
      const short8 av = *(const short8*)(&pan[0][l31 * 520 + s * 16 + l5 * 8]);
      const short8 bv = *(const short8*)(&pan[1][l31 * 520 + s * 16 + l5 * 8]);
      acc = __builtin_amdgcn_mfma_f32_32x32x16_bf16(av, bv, acc, 0, 0, 0);
    }
  }
  __syncthreads();
  float* red = (float*)pan;
  #pragma unroll
  for (int r = 0; r < 16; ++r) red[w * 1024 + r * 64 + lane] = acc[r];
  __syncthreads();
  #pragma unroll
  for (int q = 0; q < 4; ++q){
    const int fi = q * 256 + t;
    const float v = red[fi] + red[1024 + fi] + red[2048 + fi] + red[3072 + fi];
    const int rr = fi >> 6, ll = fi & 63;
    const int c = (rr & 3) + 8 * (rr >> 2) + 4 * (ll >> 5);   // m101 C-layout
    const int d = ll & 31;
    Gp[(((size_t)ns * 24 + bh) * 32 + c) * 32 + d] = v;
  }
}

// ---------------- k_attn: norms + softmax + M = proj @ attn_bd ----------------
__global__ __launch_bounds__(256)
void k_attn(const float* __restrict__ Gp, const float* __restrict__ qqp,
            const float* __restrict__ kkp, const float* __restrict__ temp,
            const float* __restrict__ proj, float* __restrict__ M)
{
  const int b = blockIdx.x, t = threadIdx.x;
  __shared__ float at[3][32][32];
  __shared__ float ninv[2][C_];
  if (t < 2 * C_){
    const int kind = t / C_, r = t - kind * C_;
    const float* P = kind ? kkp : qqp;
    float s = 0.f;
    #pragma unroll
    for (int ns = 0; ns < NB_; ++ns) s += P[((size_t)b * NB_ + ns) * C_ + r];
    ninv[kind][r] = 1.f / fmaxf(sqrtf(s), 1e-12f);
  }
  __syncthreads();
  for (int idx = t; idx < 3 * 1024; idx += 256){
    const int h = idx >> 10, rem = idx & 1023, cc = rem >> 5, dd = rem & 31;
    float g = 0.f;
    #pragma unroll
    for (int ns = 0; ns < NS_; ++ns)
      g += Gp[(((size_t)ns * 24 + b * 3 + h) * 32 + cc) * 32 + dd];
    at[h][cc][dd] = g * ninv[0][h * 32 + cc] * ninv[1][h * 32 + dd] * temp[h];
  }
  __syncthreads();
  if (t < C_){
    const int h = t >> 5, cc = t & 31;
    float m = -1e30f;
    for (int dd = 0; dd < 32; ++dd) m = fmaxf(m, at[h][cc][dd]);
    float s = 0.f;
    for (int dd = 0; dd < 32; ++dd){ const float e = expf(at[h][cc][dd] - m); at[h][cc][dd] = e; s += e; }
    const float inv = 1.f / s;
    for (int dd = 0; dd < 32; ++dd) at[h][cc][dd] *= inv;
  }
  __syncthreads();
  for (int idx = t; idx < C_ * C_; idx += 256){
    const int o = idx / 96, hd = idx - o * 96, h = hd >> 5, dd = hd & 31;
    float m = 0.f;
    #pragma unroll
    for (int cc = 0; cc < 32; ++cc)
      m = fmaf(proj[o * 96 + h * 32 + cc], at[h][cc][dd], m);
    M[(size_t)b * 9216 + idx] = m;
  }
}

extern "C" void kernel_launch(void* const* d_in, const int* in_sizes, int n_in,
                              void* d_out, int out_size, void* d_ws, size_t ws_size,
                              hipStream_t stream)
{
  const float* x     = (const float*)d_in[0];
  const float* y     = (const float*)d_in[1];
  const float* z     = (const float*)d_in[2];
  const float* temp  = (const float*)d_in[3];
  const float* q_pwc = (const float*)d_in[4];
  const float* q_dwc = (const float*)d_in[5];
  const float* k_pwc = (const float*)d_in[6];
  const float* k_dwc = (const float*)d_in[7];
  const float* v_pwc = (const float*)d_in[8];
  const float* v_dwc = (const float*)d_in[9];
  const float* proj  = (const float*)d_in[10];

  // workspace layout
  char* ws = (char*)d_ws;
  unsigned short* qb = (unsigned short*)(ws + 56623104);
  unsigned short* kb = (unsigned short*)(ws + 113246208);
  unsigned short* vb = (unsigned short*)(ws + 169869312);      // end 226,492,416
  float* qqp = (float*)(ws + 226492416);                       // 98,304
  float* kkp = (float*)(ws + 226590720);                       // 98,304
  float* Gp  = (float*)(ws + 4194304);                         // 1,769,472 (free region)
  float* M   = (float*)(ws + 8388608);                         // 294,912 (free region)
  float* out = (float*)d_out;

  k_conv_all<<<dim3(NB_, B_, 3), 768, 0, stream>>>(
      x, y, z, q_pwc, k_pwc, v_pwc, q_dwc, k_dwc, v_dwc, qb, kb, vb, qqp, kkp);
  k_gram<<<dim3(NS_, 24), 256, 0, stream>>>(qb, kb, Gp);
  k_attn<<<B_, 256, 0, stream>>>(Gp, qqp, kkp, temp, proj, M);
  k_gemm<<<dim3(HW_ / 128, B_), 256, 0, stream>>>(vb, M, out);
}